// Round 1
// 590.582 us; speedup vs baseline: 1.1854x; 1.1854x over previous
//
#include <hip/hip_runtime.h>

// Problem constants
#define BATCH 4
#define SEQ 4096
#define DM 1024
#define HALF_D 512             // DM/2 rope pairs
#define NROWS (BATCH * SEQ)    // 16384
#define NT128 528              // 32*33/2 lower-tri 128x128 tiles per batch
#define TILE_ELE 16384         // 128*128

typedef _Float16 f16x8 __attribute__((ext_vector_type(8)));
typedef _Float16 f16x4 __attribute__((ext_vector_type(4)));
typedef _Float16 f16x2 __attribute__((ext_vector_type(2)));
typedef float f32x4 __attribute__((ext_vector_type(4)));

#define AS1(p) ((const __attribute__((address_space(1))) void*)(p))
#define AS3(p) ((__attribute__((address_space(3))) void*)(p))

// ---------------- fp32 -> fp16 convert (8 elems/thread) ----------------
__global__ __launch_bounds__(256) void cvt_f32_f16(
    const float* __restrict__ src, _Float16* __restrict__ dst, int n8) {
  int i = blockIdx.x * 256 + threadIdx.x;
  if (i >= n8) return;
  const float4* s = (const float4*)src;
  float4 a = s[2 * i], b = s[2 * i + 1];
  f16x8 h;
  h[0] = (_Float16)a.x; h[1] = (_Float16)a.y;
  h[2] = (_Float16)a.z; h[3] = (_Float16)a.w;
  h[4] = (_Float16)b.x; h[5] = (_Float16)b.y;
  h[6] = (_Float16)b.z; h[7] = (_Float16)b.w;
  *(f16x8*)&dst[8 * i] = h;
}

// ---------------- RoPE apply in place on fp16 q or k ----------------
__global__ __launch_bounds__(256) void rope_apply(_Float16* __restrict__ T) {
  int idx = blockIdx.x * 256 + threadIdx.x;  // NROWS*HALF_D
  int row = idx >> 9;
  int i = idx & 511;
  int pos = row & (SEQ - 1);
  float theta = expf(-0.017988946039016f * ((float)i - 1.0f));  // 10000^(-2(i-1)/DM)
  float ang = (float)pos * theta;
  float c = cosf(ang), s = sinf(ang);
  f16x2 p = ((f16x2*)T)[idx];
  float e = (float)p[0], o = (float)p[1];
  p[0] = (_Float16)(e * c + o * s);
  p[1] = (_Float16)(o * c - e * s);
  ((f16x2*)T)[idx] = p;
}

// =====================================================================
// 256x256-tile 8-phase NT GEMM (m201-style template, f16):
//   C[m][n] = sum_k A[m][k] * B[n][k]
// BK=64, 512 threads = 8 waves (2 wr x 4 wc), per-wave 128x64 output
// (8x4 frags of 16x16), LDS 128 KiB = 2 dbuf x {A,B} x 2 half x 128x64 f16.
// Counted vmcnt(8): prefetch of K-tile kt+2 issued at phase 4 of kt (after
// the last ds_reads of dbuf[kt&1] have completed + barrier), drained at the
// NEXT group's phase-4 vmcnt -> loads stay in flight across barriers (T4).
// LDS XOR swizzle (byte ^= (row&7)<<4): applied to the global SOURCE chunk
// (global_load_lds writes linearly) and to the ds_read address (rule #21) ->
// conflict-free ds_read_b128.
// MODE 0: fp16 C row-major (Q/K projections)
// MODE 1: scores: scale 1/32, write 128x128 quadrants into packed lower-tri
//         128-tile layout (softmax/PV unchanged)
// MODE 3: V projection with transposed output: Vt[b][d][m] fp16
// =====================================================================
template <int MODE>
__global__ __launch_bounds__(512, 2) void gemm256(
    const _Float16* __restrict__ A, const _Float16* __restrict__ B,
    void* __restrict__ Cv, int K, int lda, int ldb, int ldc,
    long long strideA, long long strideB, long long strideC) {
  const int bx = blockIdx.x, by = blockIdx.y, bz = blockIdx.z;
  if (MODE == 1 && bx > by) return;  // fully above diagonal (256-granular)
  A += (size_t)bz * strideA;
  B += (size_t)bz * strideB;

  extern __shared__ __align__(16) _Float16 lds[];  // 65536 f16 = 128 KiB

  const int tid = threadIdx.x;
  const int lane = tid & 63, wave = tid >> 6;
  const int wr = wave >> 2, wc = wave & 3;   // wave grid 2x4
  const int r16 = lane & 15, quad = lane >> 4;
  const int m0 = by * 256, n0 = bx * 256;

  // ---- staging pointers: chunk c = i*512 + tid; row=c>>3 (0..127),
  // source col pre-swizzled: scol = (c&7) ^ (row&7)  (16B chunks)
  const _Float16* pA[2][2];  // [half][i]
  const _Float16* pB[2][2];
#pragma unroll
  for (int i = 0; i < 2; ++i) {
    int c = i * 512 + tid;
    int row = c >> 3;
    int scol = (c & 7) ^ (row & 7);
#pragma unroll
    for (int h = 0; h < 2; ++h) {
      pA[h][i] = A + (size_t)(m0 + h * 128 + row) * lda + scol * 8;
      pB[h][i] = B + (size_t)(n0 + h * 128 + row) * ldb + scol * 8;
    }
  }

  // stage 4 half-tiles (A.h0,A.h1,B.h0,B.h1) of one K-tile into dbuf d.
  // LDS dest = wave-uniform base + lane*16 (linear chunk order).
#define STAGE(d)                                                            \
  {                                                                         \
    _Pragma("unroll") for (int i = 0; i < 2; ++i) {                         \
      int cu = (i * 512 + wave * 64) * 8;                                   \
      _Pragma("unroll") for (int h = 0; h < 2; ++h) {                       \
        __builtin_amdgcn_global_load_lds(                                   \
            AS1(pA[h][i]), AS3(&lds[((d) * 4 + h) * 8192 + cu]), 16, 0, 0); \
        __builtin_amdgcn_global_load_lds(                                   \
            AS1(pB[h][i]), AS3(&lds[((d) * 4 + 2 + h) * 8192 + cu]), 16, 0, \
            0);                                                             \
      }                                                                     \
    }                                                                       \
    _Pragma("unroll") for (int i = 0; i < 2; ++i)                           \
        _Pragma("unroll") for (int h = 0; h < 2; ++h) {                     \
      pA[h][i] += 64;                                                       \
      pB[h][i] += 64;                                                       \
    }                                                                       \
  }

  f32x4 acc[8][4] = {};

  const int NKT = K >> 6;  // BK=64 K-tiles (>=2 always here)

  // ds_read swizzled column offsets (elems) for ks=0/1:
  // logical 16B chunk (ks*4+quad), physical = chunk ^ (row&7); row&7 == r16&7
  const int aoff0 = ((quad) ^ (r16 & 7)) * 8;
  const int aoff1 = ((4 + quad) ^ (r16 & 7)) * 8;

  // ---- prologue: stage kt0 -> dbuf0, kt1 -> dbuf1; wait kt0 landed
  STAGE(0);
  STAGE(1);
  asm volatile("s_waitcnt vmcnt(8)" ::: "memory");
  __builtin_amdgcn_s_barrier();

  for (int kt = 0; kt < NKT; ++kt) {
    const int d = kt & 1;
    const _Float16* Ab = lds + (d * 4 + wr) * 8192;
    const _Float16* Bb = lds + (d * 4 + 2 + (wc >> 1)) * 8192 + (wc & 1) * 4096;
    f16x8 af[4][2], bf[4][2];

    // ---------------- phase 1: read af(mi0-3)+bf(ni0-1); MFMA G0 ----------
#pragma unroll
    for (int mi = 0; mi < 4; ++mi) {
      af[mi][0] = *(const f16x8*)&Ab[(mi * 16 + r16) * 64 + aoff0];
      af[mi][1] = *(const f16x8*)&Ab[(mi * 16 + r16) * 64 + aoff1];
    }
#pragma unroll
    for (int ni = 0; ni < 2; ++ni) {
      bf[ni][0] = *(const f16x8*)&Bb[(ni * 16 + r16) * 64 + aoff0];
      bf[ni][1] = *(const f16x8*)&Bb[(ni * 16 + r16) * 64 + aoff1];
    }
    __builtin_amdgcn_s_barrier();
    __builtin_amdgcn_s_setprio(1);
#pragma unroll
    for (int mi = 0; mi < 4; ++mi)
#pragma unroll
      for (int ni = 0; ni < 2; ++ni) {
        acc[mi][ni] = __builtin_amdgcn_mfma_f32_16x16x32_f16(
            af[mi][0], bf[ni][0], acc[mi][ni], 0, 0, 0);
        acc[mi][ni] = __builtin_amdgcn_mfma_f32_16x16x32_f16(
            af[mi][1], bf[ni][1], acc[mi][ni], 0, 0, 0);
      }
    __builtin_amdgcn_s_setprio(0);
    __builtin_amdgcn_s_barrier();

    // ---------------- phase 2: read bf(ni2-3); MFMA G1 --------------------
#pragma unroll
    for (int ni = 2; ni < 4; ++ni) {
      bf[ni][0] = *(const f16x8*)&Bb[(ni * 16 + r16) * 64 + aoff0];
      bf[ni][1] = *(const f16x8*)&Bb[(ni * 16 + r16) * 64 + aoff1];
    }
    __builtin_amdgcn_s_barrier();
    __builtin_amdgcn_s_setprio(1);
#pragma unroll
    for (int mi = 0; mi < 4; ++mi)
#pragma unroll
      for (int ni = 2; ni < 4; ++ni) {
        acc[mi][ni] = __builtin_amdgcn_mfma_f32_16x16x32_f16(
            af[mi][0], bf[ni][0], acc[mi][ni], 0, 0, 0);
        acc[mi][ni] = __builtin_amdgcn_mfma_f32_16x16x32_f16(
            af[mi][1], bf[ni][1], acc[mi][ni], 0, 0, 0);
      }
    __builtin_amdgcn_s_setprio(0);
    __builtin_amdgcn_s_barrier();

    // ---------------- phase 3: read af(mi4-7); MFMA G2 --------------------
#pragma unroll
    for (int mi = 0; mi < 4; ++mi) {
      af[mi][0] = *(const f16x8*)&Ab[((mi + 4) * 16 + r16) * 64 + aoff0];
      af[mi][1] = *(const f16x8*)&Ab[((mi + 4) * 16 + r16) * 64 + aoff1];
    }
    __builtin_amdgcn_s_barrier();
    __builtin_amdgcn_s_setprio(1);
#pragma unroll
    for (int mi = 0; mi < 4; ++mi)
#pragma unroll
      for (int ni = 0; ni < 2; ++ni) {
        acc[mi + 4][ni] = __builtin_amdgcn_mfma_f32_16x16x32_f16(
            af[mi][0], bf[ni][0], acc[mi + 4][ni], 0, 0, 0);
        acc[mi + 4][ni] = __builtin_amdgcn_mfma_f32_16x16x32_f16(
            af[mi][1], bf[ni][1], acc[mi + 4][ni], 0, 0, 0);
      }
    __builtin_amdgcn_s_setprio(0);
    __builtin_amdgcn_s_barrier();
    // (phase-3 ending barrier: all waves' reads of dbuf[d] are complete ->
    //  phase 4 may DMA kt+2 into dbuf[d])

    // ---------------- phase 4: stage kt+2 -> dbuf[d]; MFMA G3; counted wait
    if (kt + 2 < NKT) STAGE(d);
    __builtin_amdgcn_s_setprio(1);
#pragma unroll
    for (int mi = 0; mi < 4; ++mi)
#pragma unroll
      for (int ni = 2; ni < 4; ++ni) {
        acc[mi + 4][ni] = __builtin_amdgcn_mfma_f32_16x16x32_f16(
            af[mi][0], bf[ni][0], acc[mi + 4][ni], 0, 0, 0);
        acc[mi + 4][ni] = __builtin_amdgcn_mfma_f32_16x16x32_f16(
            af[mi][1], bf[ni][1], acc[mi + 4][ni], 0, 0, 0);
      }
    __builtin_amdgcn_s_setprio(0);
    // guard kt+1's tiles: outstanding = 8 (kt+1) + [8 (kt+2) if staged]
    if (kt + 2 < NKT) {
      asm volatile("s_waitcnt vmcnt(8)" ::: "memory");
    } else if (kt + 1 < NKT) {
      asm volatile("s_waitcnt vmcnt(0)" ::: "memory");
    }
    __builtin_amdgcn_s_barrier();
  }
#undef STAGE

  // ---- epilogues ----
  if (MODE == 0) {
    _Float16* C = (_Float16*)Cv;
#pragma unroll
    for (int mi = 0; mi < 8; ++mi)
#pragma unroll
      for (int ni = 0; ni < 4; ++ni)
#pragma unroll
        for (int r = 0; r < 4; ++r) {
          int grow = m0 + wr * 128 + mi * 16 + quad * 4 + r;
          int gcol = n0 + wc * 64 + ni * 16 + r16;
          C[(size_t)grow * ldc + gcol] = (_Float16)acc[mi][ni][r];
        }
  } else if (MODE == 1) {
    // quadrant (128-granular) indices; wave-uniform
    int i128 = by * 2 + wr;
    int j128 = bx * 2 + (wc >> 1);
    if (j128 <= i128) {
      _Float16* T = (_Float16*)Cv + (size_t)bz * strideC +
                    (size_t)(i128 * (i128 + 1) / 2 + j128) * TILE_ELE;
#pragma unroll
      for (int mi = 0; mi < 8; ++mi)
#pragma unroll
        for (int ni = 0; ni < 4; ++ni)
#pragma unroll
          for (int r = 0; r < 4; ++r) {
            int lr = mi * 16 + quad * 4 + r;          // 0..127
            int lc = (wc & 1) * 64 + ni * 16 + r16;   // 0..127
            T[lr * 128 + lc] = (_Float16)(acc[mi][ni][r] * 0.03125f);
          }
    }
  } else {  // MODE 3: Vt[b][d][m]
    _Float16* C = (_Float16*)Cv;
#pragma unroll
    for (int mi = 0; mi < 8; ++mi)
#pragma unroll
      for (int ni = 0; ni < 4; ++ni) {
        int gcol = n0 + wc * 64 + ni * 16 + r16;              // d
        int growb = m0 + wr * 128 + mi * 16 + quad * 4;       // m base
        int b = growb >> 12;
        int m = growb & (SEQ - 1);
        f16x4 t;
#pragma unroll
        for (int r = 0; r < 4; ++r) t[r] = (_Float16)acc[mi][ni][r];
        *(f16x4*)&C[((size_t)b * DM + gcol) * SEQ + m] = t;
      }
  }
}

// ---------------- m97-style NT GEMM (kept for PV, MODE 2 only) ----------------
template <int MODE>
__global__ __launch_bounds__(256) void gemm128(
    const _Float16* __restrict__ A, const _Float16* __restrict__ B,
    void* __restrict__ Cv, int K, int lda, int ldb, int ldc,
    long long strideA, long long strideB, long long strideC) {
  int bx = blockIdx.x, bz = blockIdx.z;
  int by = (MODE == 2) ? (31 - blockIdx.y) : blockIdx.y;  // heavy tiles first
  if (MODE == 1 && bx > by) return;
  A += (size_t)bz * strideA;
  B += (size_t)bz * strideB;

  __shared__ __align__(16) _Float16 sA[128 * 64];
  __shared__ __align__(16) _Float16 sB[128 * 64];

  const int tid = threadIdx.x;
  const int lane = tid & 63, wave = tid >> 6;
  const int wm = (wave & 1) * 64, wn = (wave >> 1) * 64;
  const int r16 = lane & 15, quad = lane >> 4;
  const int m0 = by * 128, n0 = bx * 128;
  const int triBase = by * (by + 1) / 2;

  f32x4 acc[4][4] = {};

  const int nkt = (MODE == 2) ? (by + 1) * 2 : (K >> 6);

  for (int kt = 0; kt < nkt; ++kt) {
#pragma unroll
    for (int j = 0; j < 4; ++j) {
      int c = j * 256 + tid;
      int row = c >> 3, col = c & 7;
      const _Float16* gA;
      if (MODE == 2) {
        gA = A + (size_t)(triBase + (kt >> 1)) * TILE_ELE + row * 128 +
             (kt & 1) * 64 + col * 8;
      } else {
        gA = A + (size_t)(m0 + row) * lda + kt * 64 + col * 8;
      }
      const _Float16* gB = B + (size_t)(n0 + row) * ldb + kt * 64 + col * 8;
      __builtin_amdgcn_global_load_lds(AS1(gA), AS3(&sA[(j * 256 + wave * 64) * 8]), 16, 0, 0);
      __builtin_amdgcn_global_load_lds(AS1(gB), AS3(&sB[(j * 256 + wave * 64) * 8]), 16, 0, 0);
    }
    __syncthreads();

#pragma unroll
    for (int ks = 0; ks < 2; ++ks) {
      f16x8 af[4], bf[4];
#pragma unroll
      for (int i = 0; i < 4; ++i) {
        af[i] = *(const f16x8*)&sA[(wm + i * 16 + r16) * 64 + ks * 32 + quad * 8];
        bf[i] = *(const f16x8*)&sB[(wn + i * 16 + r16) * 64 + ks * 32 + quad * 8];
      }
#pragma unroll
      for (int mi = 0; mi < 4; ++mi)
#pragma unroll
        for (int ni = 0; ni < 4; ++ni)
          acc[mi][ni] = __builtin_amdgcn_mfma_f32_16x16x32_f16(
              af[mi], bf[ni], acc[mi][ni], 0, 0, 0);
    }
    __syncthreads();
  }

  if (MODE == 2) {
    float* C = (float*)Cv + (size_t)bz * strideC;
#pragma unroll
    for (int mi = 0; mi < 4; ++mi)
#pragma unroll
      for (int ni = 0; ni < 4; ++ni)
#pragma unroll
        for (int r = 0; r < 4; ++r) {
          int grow = m0 + wm + mi * 16 + quad * 4 + r;
          int gcol = n0 + wn + ni * 16 + r16;
          C[(size_t)grow * ldc + gcol] = acc[mi][ni][r];
        }
  }
}

// ---------------- row softmax on packed fp16 scores, fp16 P in place ----------------
__global__ __launch_bounds__(256) void softmax_rows(_Float16* __restrict__ Sp) {
  __shared__ float vals[SEQ];
  __shared__ float red[256];
  int row = blockIdx.x;  // 0..NROWS-1
  int b = row >> 12;
  int q = row & (SEQ - 1);
  int i = q >> 7, r = q & 127;
  _Float16* base = Sp + (size_t)b * ((size_t)NT128 * TILE_ELE) +
                   (size_t)(i * (i + 1) / 2) * TILE_ELE + (size_t)r * 128;
  int tid = threadIdx.x;
  int Kv = q + 1;
  float m = -__builtin_inff();
  for (int kb = tid * 8; kb + 8 <= Kv; kb += 2048) {
    f16x8 v8 = *(const f16x8*)&base[(kb >> 7) * TILE_ELE + (kb & 127)];
#pragma unroll
    for (int t = 0; t < 8; ++t) {
      float v = (float)v8[t];
      vals[kb + t] = v;
      m = fmaxf(m, v);
    }
  }
  if (tid == 0) {
    for (int k = Kv & ~7; k < Kv; ++k) {
      float v = (float)base[(k >> 7) * TILE_ELE + (k & 127)];
      vals[k] = v;
      m = fmaxf(m, v);
    }
  }
  red[tid] = m;
  __syncthreads();
  for (int s = 128; s > 0; s >>= 1) {
    if (tid < s) red[tid] = fmaxf(red[tid], red[tid + s]);
    __syncthreads();
  }
  m = red[0];
  __syncthreads();
  float l = 0.f;
  for (int k = tid; k < Kv; k += 256) {
    float e = __expf(vals[k] - m);
    vals[k] = e;
    l += e;
  }
  red[tid] = l;
  __syncthreads();
  for (int s = 128; s > 0; s >>= 1) {
    if (tid < s) red[tid] += red[tid + s];
    __syncthreads();
  }
  float inv = 1.0f / red[0];
  int Kend = (i + 1) * 128;
  for (int kb = tid * 8; kb < Kend; kb += 2048) {
    f16x8 p;
#pragma unroll
    for (int t = 0; t < 8; ++t) {
      int k = kb + t;
      p[t] = (k < Kv) ? (_Float16)(vals[k] * inv) : (_Float16)0.f;
    }
    *(f16x8*)&base[(kb >> 7) * TILE_ELE + (kb & 127)] = p;
  }
}

extern "C" void kernel_launch(void* const* d_in, const int* in_sizes, int n_in,
                              void* d_out, int out_size, void* d_ws,
                              size_t ws_size, hipStream_t stream) {
  const float* x = (const float*)d_in[0];
  const float* wq = (const float*)d_in[1];
  const float* wk = (const float*)d_in[2];
  const float* wv = (const float*)d_in[3];

  // Workspace layout (~98 MiB), unchanged:
  //   [0, 69206016)            : Sp (packed tri fp16 scores)
  //     aliased early: xh [0,33554432) ; wqh/wkh/wvh [33554432, ...)
  //   [69206016, +33554432)    : vth (fp16 V^T, [B][DM][SEQ])
  char* ws = (char*)d_ws;
  _Float16* Sp = (_Float16*)ws;
  _Float16* xh = (_Float16*)ws;
  _Float16* wqh = (_Float16*)(ws + 33554432);
  _Float16* wkh = wqh + (size_t)DM * DM;
  _Float16* wvh = wkh + (size_t)DM * DM;
  _Float16* vth = (_Float16*)(ws + 69206016);
  _Float16* qh = (_Float16*)d_out;
  _Float16* kh = qh + (size_t)NROWS * DM;
  (void)ws_size; (void)in_sizes; (void)n_in; (void)out_size;

  // allow 128 KiB dynamic LDS for the 8-phase kernels (host-side, capture-safe)
  static int attr_done = 0;
  if (!attr_done) {
    hipFuncSetAttribute(reinterpret_cast<const void*>(&gemm256<0>),
                        hipFuncAttributeMaxDynamicSharedMemorySize, 131072);
    hipFuncSetAttribute(reinterpret_cast<const void*>(&gemm256<1>),
                        hipFuncAttributeMaxDynamicSharedMemorySize, 131072);
    hipFuncSetAttribute(reinterpret_cast<const void*>(&gemm256<3>),
                        hipFuncAttributeMaxDynamicSharedMemorySize, 131072);
    attr_done = 1;
  }

  // 1. fp32 -> fp16 converts
  cvt_f32_f16<<<8192, 256, 0, stream>>>(x, xh, NROWS * DM / 8);
  cvt_f32_f16<<<512, 256, 0, stream>>>(wq, wqh, DM * DM / 8);
  cvt_f32_f16<<<512, 256, 0, stream>>>(wk, wkh, DM * DM / 8);
  cvt_f32_f16<<<512, 256, 0, stream>>>(wv, wvh, DM * DM / 8);

  // 2. QKV projections (256x256 8-phase; grid = 256 blocks = 1/CU exactly)
  dim3 gp(DM / 256, NROWS / 256, 1);  // (4, 64)
  gemm256<0><<<gp, 512, 131072, stream>>>(xh, wqh, qh, DM, DM, DM, DM, 0, 0, 0);
  gemm256<0><<<gp, 512, 131072, stream>>>(xh, wkh, kh, DM, DM, DM, DM, 0, 0, 0);
  gemm256<3><<<gp, 512, 131072, stream>>>(xh, wvh, vth, DM, DM, DM, 0, 0, 0, 0);

  // 3. RoPE q,k in place
  rope_apply<<<NROWS * HALF_D / 256, 256, 0, stream>>>(qh);
  rope_apply<<<NROWS * HALF_D / 256, 256, 0, stream>>>(kh);

  // 4. scores (256-tile 8-phase GEMM; epilogue -> packed lower-tri 128-tiles)
  gemm256<1><<<dim3(SEQ / 256, SEQ / 256, BATCH), 512, 131072, stream>>>(
      qh, kh, Sp, DM, DM, DM, 128, (long long)SEQ * DM, (long long)SEQ * DM,
      (long long)NT128 * TILE_ELE);

  // 5. softmax rows -> fp16 P in place (unchanged)
  softmax_rows<<<NROWS, 256, 0, stream>>>(Sp);

  // 6. O = P @ V  (unchanged 128-tile kernel; next round's target)
  gemm128<2><<<dim3(DM / 128, SEQ / 128, BATCH), 256, 0, stream>>>(
      Sp, vth, out_size ? (void*)d_out : (void*)d_out, SEQ, 0, SEQ, DM,
      (long long)NT128 * TILE_ELE, (long long)DM * SEQ, (long long)SEQ * DM);
}

// Round 2
// 530.900 us; speedup vs baseline: 1.3186x; 1.1124x over previous
//
#include <hip/hip_runtime.h>

// Problem constants
#define BATCH 4
#define SEQ 4096
#define DM 1024
#define HALF_D 512             // DM/2 rope pairs
#define NROWS (BATCH * SEQ)    // 16384
#define NT128 528              // 32*33/2 lower-tri 128x128 tiles per batch
#define TILE_ELE 16384         // 128*128

typedef _Float16 f16x8 __attribute__((ext_vector_type(8)));
typedef _Float16 f16x4 __attribute__((ext_vector_type(4)));
typedef _Float16 f16x2 __attribute__((ext_vector_type(2)));
typedef float f32x4 __attribute__((ext_vector_type(4)));

#define AS1(p) ((const __attribute__((address_space(1))) void*)(p))
#define AS3(p) ((__attribute__((address_space(3))) void*)(p))

// ---------------- fp32 -> fp16 convert (8 elems/thread) ----------------
__global__ __launch_bounds__(256) void cvt_f32_f16(
    const float* __restrict__ src, _Float16* __restrict__ dst, int n8) {
  int i = blockIdx.x * 256 + threadIdx.x;
  if (i >= n8) return;
  const float4* s = (const float4*)src;
  float4 a = s[2 * i], b = s[2 * i + 1];
  f16x8 h;
  h[0] = (_Float16)a.x; h[1] = (_Float16)a.y;
  h[2] = (_Float16)a.z; h[3] = (_Float16)a.w;
  h[4] = (_Float16)b.x; h[5] = (_Float16)b.y;
  h[6] = (_Float16)b.z; h[7] = (_Float16)b.w;
  *(f16x8*)&dst[8 * i] = h;
}

// ---------------- RoPE apply in place on fp16 q or k ----------------
__global__ __launch_bounds__(256) void rope_apply(_Float16* __restrict__ T) {
  int idx = blockIdx.x * 256 + threadIdx.x;  // NROWS*HALF_D
  int row = idx >> 9;
  int i = idx & 511;
  int pos = row & (SEQ - 1);
  float theta = expf(-0.017988946039016f * ((float)i - 1.0f));  // 10000^(-2(i-1)/DM)
  float ang = (float)pos * theta;
  float c = cosf(ang), s = sinf(ang);
  f16x2 p = ((f16x2*)T)[idx];
  float e = (float)p[0], o = (float)p[1];
  p[0] = (_Float16)(e * c + o * s);
  p[1] = (_Float16)(o * c - e * s);
  ((f16x2*)T)[idx] = p;
}

// =====================================================================
// 256x256-tile 8-phase NT GEMM (m201-style template, f16):
//   C[m][n] = sum_k A[m][k] * B[n][k]
// BK=64, 512 threads = 8 waves (2 wr x 4 wc), per-wave 128x64 output.
// Counted vmcnt(8), LDS XOR swizzle both-sides, setprio around MFMA.
// MODE 0: fp16 C row-major (Q/K projections)
// MODE 1: scores: scale 1/32, 128x128 quadrants -> packed lower-tri tiles
// MODE 3: V projection with transposed output: Vt[b][d][m] fp16
// =====================================================================
template <int MODE>
__global__ __launch_bounds__(512, 2) void gemm256(
    const _Float16* __restrict__ A, const _Float16* __restrict__ B,
    void* __restrict__ Cv, int K, int lda, int ldb, int ldc,
    long long strideA, long long strideB, long long strideC) {
  const int bx = blockIdx.x, by = blockIdx.y, bz = blockIdx.z;
  if (MODE == 1 && bx > by) return;  // fully above diagonal (256-granular)
  A += (size_t)bz * strideA;
  B += (size_t)bz * strideB;

  extern __shared__ __align__(16) _Float16 lds[];  // 65536 f16 = 128 KiB

  const int tid = threadIdx.x;
  const int lane = tid & 63, wave = tid >> 6;
  const int wr = wave >> 2, wc = wave & 3;   // wave grid 2x4
  const int r16 = lane & 15, quad = lane >> 4;
  const int m0 = by * 256, n0 = bx * 256;

  // staging pointers: chunk c = i*512 + tid; row=c>>3 (0..127),
  // source col pre-swizzled: scol = (c&7) ^ (row&7)  (16B chunks)
  const _Float16* pA[2][2];  // [half][i]
  const _Float16* pB[2][2];
#pragma unroll
  for (int i = 0; i < 2; ++i) {
    int c = i * 512 + tid;
    int row = c >> 3;
    int scol = (c & 7) ^ (row & 7);
#pragma unroll
    for (int h = 0; h < 2; ++h) {
      pA[h][i] = A + (size_t)(m0 + h * 128 + row) * lda + scol * 8;
      pB[h][i] = B + (size_t)(n0 + h * 128 + row) * ldb + scol * 8;
    }
  }

#define STAGE(d)                                                            \
  {                                                                         \
    _Pragma("unroll") for (int i = 0; i < 2; ++i) {                         \
      int cu = (i * 512 + wave * 64) * 8;                                   \
      _Pragma("unroll") for (int h = 0; h < 2; ++h) {                       \
        __builtin_amdgcn_global_load_lds(                                   \
            AS1(pA[h][i]), AS3(&lds[((d) * 4 + h) * 8192 + cu]), 16, 0, 0); \
        __builtin_amdgcn_global_load_lds(                                   \
            AS1(pB[h][i]), AS3(&lds[((d) * 4 + 2 + h) * 8192 + cu]), 16, 0, \
            0);                                                             \
      }                                                                     \
    }                                                                       \
    _Pragma("unroll") for (int i = 0; i < 2; ++i)                           \
        _Pragma("unroll") for (int h = 0; h < 2; ++h) {                     \
      pA[h][i] += 64;                                                       \
      pB[h][i] += 64;                                                       \
    }                                                                       \
  }

  f32x4 acc[8][4] = {};

  const int NKT = K >> 6;  // BK=64 K-tiles

  const int aoff0 = ((quad) ^ (r16 & 7)) * 8;
  const int aoff1 = ((4 + quad) ^ (r16 & 7)) * 8;

  STAGE(0);
  STAGE(1);
  asm volatile("s_waitcnt vmcnt(8)" ::: "memory");
  __builtin_amdgcn_s_barrier();

  for (int kt = 0; kt < NKT; ++kt) {
    const int d = kt & 1;
    const _Float16* Ab = lds + (d * 4 + wr) * 8192;
    const _Float16* Bb = lds + (d * 4 + 2 + (wc >> 1)) * 8192 + (wc & 1) * 4096;
    f16x8 af[4][2], bf[4][2];

    // phase 1: read af(mi0-3)+bf(ni0-1); MFMA G0
#pragma unroll
    for (int mi = 0; mi < 4; ++mi) {
      af[mi][0] = *(const f16x8*)&Ab[(mi * 16 + r16) * 64 + aoff0];
      af[mi][1] = *(const f16x8*)&Ab[(mi * 16 + r16) * 64 + aoff1];
    }
#pragma unroll
    for (int ni = 0; ni < 2; ++ni) {
      bf[ni][0] = *(const f16x8*)&Bb[(ni * 16 + r16) * 64 + aoff0];
      bf[ni][1] = *(const f16x8*)&Bb[(ni * 16 + r16) * 64 + aoff1];
    }
    __builtin_amdgcn_s_barrier();
    __builtin_amdgcn_s_setprio(1);
#pragma unroll
    for (int mi = 0; mi < 4; ++mi)
#pragma unroll
      for (int ni = 0; ni < 2; ++ni) {
        acc[mi][ni] = __builtin_amdgcn_mfma_f32_16x16x32_f16(
            af[mi][0], bf[ni][0], acc[mi][ni], 0, 0, 0);
        acc[mi][ni] = __builtin_amdgcn_mfma_f32_16x16x32_f16(
            af[mi][1], bf[ni][1], acc[mi][ni], 0, 0, 0);
      }
    __builtin_amdgcn_s_setprio(0);
    __builtin_amdgcn_s_barrier();

    // phase 2: read bf(ni2-3); MFMA G1
#pragma unroll
    for (int ni = 2; ni < 4; ++ni) {
      bf[ni][0] = *(const f16x8*)&Bb[(ni * 16 + r16) * 64 + aoff0];
      bf[ni][1] = *(const f16x8*)&Bb[(ni * 16 + r16) * 64 + aoff1];
    }
    __builtin_amdgcn_s_barrier();
    __builtin_amdgcn_s_setprio(1);
#pragma unroll
    for (int mi = 0; mi < 4; ++mi)
#pragma unroll
      for (int ni = 2; ni < 4; ++ni) {
        acc[mi][ni] = __builtin_amdgcn_mfma_f32_16x16x32_f16(
            af[mi][0], bf[ni][0], acc[mi][ni], 0, 0, 0);
        acc[mi][ni] = __builtin_amdgcn_mfma_f32_16x16x32_f16(
            af[mi][1], bf[ni][1], acc[mi][ni], 0, 0, 0);
      }
    __builtin_amdgcn_s_setprio(0);
    __builtin_amdgcn_s_barrier();

    // phase 3: read af(mi4-7); MFMA G2
#pragma unroll
    for (int mi = 0; mi < 4; ++mi) {
      af[mi][0] = *(const f16x8*)&Ab[((mi + 4) * 16 + r16) * 64 + aoff0];
      af[mi][1] = *(const f16x8*)&Ab[((mi + 4) * 16 + r16) * 64 + aoff1];
    }
    __builtin_amdgcn_s_barrier();
    __builtin_amdgcn_s_setprio(1);
#pragma unroll
    for (int mi = 0; mi < 4; ++mi)
#pragma unroll
      for (int ni = 0; ni < 2; ++ni) {
        acc[mi + 4][ni] = __builtin_amdgcn_mfma_f32_16x16x32_f16(
            af[mi][0], bf[ni][0], acc[mi + 4][ni], 0, 0, 0);
        acc[mi + 4][ni] = __builtin_amdgcn_mfma_f32_16x16x32_f16(
            af[mi][1], bf[ni][1], acc[mi + 4][ni], 0, 0, 0);
      }
    __builtin_amdgcn_s_setprio(0);
    __builtin_amdgcn_s_barrier();

    // phase 4: stage kt+2 -> dbuf[d]; MFMA G3; counted wait
    if (kt + 2 < NKT) STAGE(d);
    __builtin_amdgcn_s_setprio(1);
#pragma unroll
    for (int mi = 0; mi < 4; ++mi)
#pragma unroll
      for (int ni = 2; ni < 4; ++ni) {
        acc[mi + 4][ni] = __builtin_amdgcn_mfma_f32_16x16x32_f16(
            af[mi][0], bf[ni][0], acc[mi + 4][ni], 0, 0, 0);
        acc[mi + 4][ni] = __builtin_amdgcn_mfma_f32_16x16x32_f16(
            af[mi][1], bf[ni][1], acc[mi + 4][ni], 0, 0, 0);
      }
    __builtin_amdgcn_s_setprio(0);
    if (kt + 2 < NKT) {
      asm volatile("s_waitcnt vmcnt(8)" ::: "memory");
    } else if (kt + 1 < NKT) {
      asm volatile("s_waitcnt vmcnt(0)" ::: "memory");
    }
    __builtin_amdgcn_s_barrier();
  }
#undef STAGE

  // ---- epilogues ----
  if (MODE == 0) {
    _Float16* C = (_Float16*)Cv;
#pragma unroll
    for (int mi = 0; mi < 8; ++mi)
#pragma unroll
      for (int ni = 0; ni < 4; ++ni)
#pragma unroll
        for (int r = 0; r < 4; ++r) {
          int grow = m0 + wr * 128 + mi * 16 + quad * 4 + r;
          int gcol = n0 + wc * 64 + ni * 16 + r16;
          C[(size_t)grow * ldc + gcol] = (_Float16)acc[mi][ni][r];
        }
  } else if (MODE == 1) {
    int i128 = by * 2 + wr;
    int j128 = bx * 2 + (wc >> 1);
    if (j128 <= i128) {
      _Float16* T = (_Float16*)Cv + (size_t)bz * strideC +
                    (size_t)(i128 * (i128 + 1) / 2 + j128) * TILE_ELE;
#pragma unroll
      for (int mi = 0; mi < 8; ++mi)
#pragma unroll
        for (int ni = 0; ni < 4; ++ni)
#pragma unroll
          for (int r = 0; r < 4; ++r) {
            int lr = mi * 16 + quad * 4 + r;          // 0..127
            int lc = (wc & 1) * 64 + ni * 16 + r16;   // 0..127
            T[lr * 128 + lc] = (_Float16)(acc[mi][ni][r] * 0.03125f);
          }
    }
  } else {  // MODE 3: Vt[b][d][m]
    _Float16* C = (_Float16*)Cv;
#pragma unroll
    for (int mi = 0; mi < 8; ++mi)
#pragma unroll
      for (int ni = 0; ni < 4; ++ni) {
        int gcol = n0 + wc * 64 + ni * 16 + r16;              // d
        int growb = m0 + wr * 128 + mi * 16 + quad * 4;       // m base
        int b = growb >> 12;
        int m = growb & (SEQ - 1);
        f16x4 t;
#pragma unroll
        for (int r = 0; r < 4; ++r) t[r] = (_Float16)acc[mi][ni][r];
        *(f16x4*)&C[((size_t)b * DM + gcol) * SEQ + m] = t;
      }
  }
}

// =====================================================================
// PV: O = P @ V, 8-phase 128x256-tile NT GEMM.
// A = packed lower-tri fp16 P (128-tiles), B = V^T [B][DM][SEQ], C fp32.
// M-tile = 128 rows (one packed-tri row, exact causal K = (by+1)*128),
// N-tile = 256 d-cols, BK = 64, 512 thr = 8 waves (2x4), 64x64 per wave.
// LDS 96 KiB = 2 dbuf x (A 128x64 + B 256x64) f16, XOR-swizzled both sides.
// Counted vmcnt(6) (6 loads/K-tile, depth-2 prefetch); stage into dbuf[d]
// only after the barrier that follows the last MFMA consuming dbuf[d].
// Grid: 512 blocks, 1D, rank-major heavy-first across batches: blocks of
// equal K run concurrently (the 4 bx blocks share the P panel in cache),
// and (64,2),(62,4).. kt-unit pairing balances CUs at 2 blocks/CU.
// =====================================================================
__global__ __launch_bounds__(512, 1) void gemm_pv(
    const _Float16* __restrict__ P, const _Float16* __restrict__ Vt,
    float* __restrict__ O) {
  const int id = blockIdx.x;
  const int by = 31 - (id >> 4);   // heavy (large K) first
  const int bx = id & 3;           // DM/256 col-tile
  const int bz = (id >> 2) & 3;    // batch

  extern __shared__ __align__(16) _Float16 lds[];  // 49152 f16 = 96 KiB

  const int tid = threadIdx.x;
  const int lane = tid & 63, wave = tid >> 6;
  const int wr = wave >> 2, wc = wave & 3;
  const int r16 = lane & 15, quad = lane >> 4;
  const int n0 = bx * 256;

  const _Float16* Pb = P + (size_t)bz * ((size_t)NT128 * TILE_ELE) +
                       (size_t)(by * (by + 1) / 2) * TILE_ELE;
  const _Float16* Vb = Vt + (size_t)bz * ((size_t)DM * SEQ) +
                       (size_t)n0 * SEQ;

  const int NKT = (by + 1) * 2;  // even, >= 2

  // stage K-tile t into dbuf dd: A 1024 chunks (2/thr), B 2048 chunks (4/thr)
#define PV_STAGE(t, dd)                                                      \
  {                                                                          \
    _Pragma("unroll") for (int i = 0; i < 2; ++i) {                          \
      int c = i * 512 + tid;                                                 \
      int row = c >> 3;                                                      \
      int scol = (c & 7) ^ (row & 7);                                        \
      const _Float16* gA = Pb + (size_t)((t) >> 1) * TILE_ELE + row * 128 +  \
                           ((t) & 1) * 64 + scol * 8;                        \
      __builtin_amdgcn_global_load_lds(                                      \
          AS1(gA), AS3(&lds[(dd) * 24576 + (i * 512 + wave * 64) * 8]), 16, \
          0, 0);                                                             \
    }                                                                        \
    _Pragma("unroll") for (int i = 0; i < 4; ++i) {                          \
      int c = i * 512 + tid;                                                 \
      int row = c >> 3;                                                      \
      int scol = (c & 7) ^ (row & 7);                                        \
      const _Float16* gB = Vb + (size_t)row * SEQ + (t) * 64 + scol * 8;     \
      __builtin_amdgcn_global_load_lds(                                      \
          AS1(gB),                                                           \
          AS3(&lds[(dd) * 24576 + 8192 + (i * 512 + wave * 64) * 8]), 16, 0, \
          0);                                                                \
    }                                                                        \
  }

  f32x4 acc[4][4] = {};

  const int aoff0 = ((quad) ^ (r16 & 7)) * 8;
  const int aoff1 = ((4 + quad) ^ (r16 & 7)) * 8;
  const int arow = (wr * 64 + r16) * 64;
  const int brow = (wc * 64 + r16) * 64;

  // prologue: tiles 0,1 in flight; wait tile 0
  PV_STAGE(0, 0);
  PV_STAGE(1, 1);
  asm volatile("s_waitcnt vmcnt(6)" ::: "memory");
  __builtin_amdgcn_s_barrier();

  for (int kt = 0; kt < NKT; ++kt) {
    const int d = kt & 1;
    const _Float16* Ab = lds + d * 24576;
    const _Float16* Bb = Ab + 8192;
    f16x8 af[4][2], bf[4][2];

    // ---- phase A: all 16 ds_reads; MFMA G0 (ni 0-1) ----
#pragma unroll
    for (int mi = 0; mi < 4; ++mi) {
      af[mi][0] = *(const f16x8*)&Ab[arow + mi * 16 * 64 + aoff0];
      af[mi][1] = *(const f16x8*)&Ab[arow + mi * 16 * 64 + aoff1];
    }
#pragma unroll
    for (int ni = 0; ni < 4; ++ni) {
      bf[ni][0] = *(const f16x8*)&Bb[brow + ni * 16 * 64 + aoff0];
      bf[ni][1] = *(const f16x8*)&Bb[brow + ni * 16 * 64 + aoff1];
    }
    __builtin_amdgcn_s_barrier();
    __builtin_amdgcn_s_setprio(1);
#pragma unroll
    for (int mi = 0; mi < 4; ++mi)
#pragma unroll
      for (int ni = 0; ni < 2; ++ni) {
        acc[mi][ni] = __builtin_amdgcn_mfma_f32_16x16x32_f16(
            af[mi][0], bf[ni][0], acc[mi][ni], 0, 0, 0);
        acc[mi][ni] = __builtin_amdgcn_mfma_f32_16x16x32_f16(
            af[mi][1], bf[ni][1], acc[mi][ni], 0, 0, 0);
      }
    __builtin_amdgcn_s_setprio(0);
    __builtin_amdgcn_s_barrier();

    // ---- phase B: MFMA G1 (ni 2-3); then stage kt+2; counted wait ----
    __builtin_amdgcn_s_setprio(1);
#pragma unroll
    for (int mi = 0; mi < 4; ++mi)
#pragma unroll
      for (int ni = 2; ni < 4; ++ni) {
        acc[mi][ni] = __builtin_amdgcn_mfma_f32_16x16x32_f16(
            af[mi][0], bf[ni][0], acc[mi][ni], 0, 0, 0);
        acc[mi][ni] = __builtin_amdgcn_mfma_f32_16x16x32_f16(
            af[mi][1], bf[ni][1], acc[mi][ni], 0, 0, 0);
      }
    __builtin_amdgcn_s_setprio(0);
    __builtin_amdgcn_s_barrier();  // all waves consumed dbuf[d]
    if (kt + 2 < NKT) {
      PV_STAGE(kt + 2, d);
      asm volatile("s_waitcnt vmcnt(6)" ::: "memory");  // tile kt+1 landed
    } else if (kt + 1 < NKT) {
      asm volatile("s_waitcnt vmcnt(0)" ::: "memory");
    }
    __builtin_amdgcn_s_barrier();  // tile kt+1 visible to all waves
  }
#undef PV_STAGE

  // ---- epilogue: fp32 C[b][m][d] ----
  float* C = O + (size_t)bz * ((size_t)SEQ * DM);
#pragma unroll
  for (int mi = 0; mi < 4; ++mi)
#pragma unroll
    for (int ni = 0; ni < 4; ++ni)
#pragma unroll
      for (int r = 0; r < 4; ++r) {
        int grow = by * 128 + wr * 64 + mi * 16 + quad * 4 + r;
        int gcol = n0 + wc * 64 + ni * 16 + r16;
        C[(size_t)grow * DM + gcol] = acc[mi][ni][r];
      }
}

// ---------------- row softmax on packed fp16 scores, fp16 P in place ----------------
__global__ __launch_bounds__(256) void softmax_rows(_Float16* __restrict__ Sp) {
  __shared__ float vals[SEQ];
  __shared__ float red[256];
  int row = blockIdx.x;  // 0..NROWS-1
  int b = row >> 12;
  int q = row & (SEQ - 1);
  int i = q >> 7, r = q & 127;
  _Float16* base = Sp + (size_t)b * ((size_t)NT128 * TILE_ELE) +
                   (size_t)(i * (i + 1) / 2) * TILE_ELE + (size_t)r * 128;
  int tid = threadIdx.x;
  int Kv = q + 1;
  float m = -__builtin_inff();
  for (int kb = tid * 8; kb + 8 <= Kv; kb += 2048) {
    f16x8 v8 = *(const f16x8*)&base[(kb >> 7) * TILE_ELE + (kb & 127)];
#pragma unroll
    for (int t = 0; t < 8; ++t) {
      float v = (float)v8[t];
      vals[kb + t] = v;
      m = fmaxf(m, v);
    }
  }
  if (tid == 0) {
    for (int k = Kv & ~7; k < Kv; ++k) {
      float v = (float)base[(k >> 7) * TILE_ELE + (k & 127)];
      vals[k] = v;
      m = fmaxf(m, v);
    }
  }
  red[tid] = m;
  __syncthreads();
  for (int s = 128; s > 0; s >>= 1) {
    if (tid < s) red[tid] = fmaxf(red[tid], red[tid + s]);
    __syncthreads();
  }
  m = red[0];
  __syncthreads();
  float l = 0.f;
  for (int k = tid; k < Kv; k += 256) {
    float e = __expf(vals[k] - m);
    vals[k] = e;
    l += e;
  }
  red[tid] = l;
  __syncthreads();
  for (int s = 128; s > 0; s >>= 1) {
    if (tid < s) red[tid] += red[tid + s];
    __syncthreads();
  }
  float inv = 1.0f / red[0];
  int Kend = (i + 1) * 128;
  for (int kb = tid * 8; kb < Kend; kb += 2048) {
    f16x8 p;
#pragma unroll
    for (int t = 0; t < 8; ++t) {
      int k = kb + t;
      p[t] = (k < Kv) ? (_Float16)(vals[k] * inv) : (_Float16)0.f;
    }
    *(f16x8*)&base[(kb >> 7) * TILE_ELE + (kb & 127)] = p;
  }
}

extern "C" void kernel_launch(void* const* d_in, const int* in_sizes, int n_in,
                              void* d_out, int out_size, void* d_ws,
                              size_t ws_size, hipStream_t stream) {
  const float* x = (const float*)d_in[0];
  const float* wq = (const float*)d_in[1];
  const float* wk = (const float*)d_in[2];
  const float* wv = (const float*)d_in[3];

  // Workspace layout (~98 MiB), unchanged:
  //   [0, 69206016)            : Sp (packed tri fp16 scores)
  //     aliased early: xh [0,33554432) ; wqh/wkh/wvh [33554432, ...)
  //   [69206016, +33554432)    : vth (fp16 V^T, [B][DM][SEQ])
  char* ws = (char*)d_ws;
  _Float16* Sp = (_Float16*)ws;
  _Float16* xh = (_Float16*)ws;
  _Float16* wqh = (_Float16*)(ws + 33554432);
  _Float16* wkh = wqh + (size_t)DM * DM;
  _Float16* wvh = wkh + (size_t)DM * DM;
  _Float16* vth = (_Float16*)(ws + 69206016);
  _Float16* qh = (_Float16*)d_out;
  _Float16* kh = qh + (size_t)NROWS * DM;
  (void)ws_size; (void)in_sizes; (void)n_in; (void)out_size;

  // allow big dynamic LDS for the 8-phase kernels (host-side, capture-safe)
  static int attr_done = 0;
  if (!attr_done) {
    hipFuncSetAttribute(reinterpret_cast<const void*>(&gemm256<0>),
                        hipFuncAttributeMaxDynamicSharedMemorySize, 131072);
    hipFuncSetAttribute(reinterpret_cast<const void*>(&gemm256<1>),
                        hipFuncAttributeMaxDynamicSharedMemorySize, 131072);
    hipFuncSetAttribute(reinterpret_cast<const void*>(&gemm256<3>),
                        hipFuncAttributeMaxDynamicSharedMemorySize, 131072);
    hipFuncSetAttribute(reinterpret_cast<const void*>(&gemm_pv),
                        hipFuncAttributeMaxDynamicSharedMemorySize, 98304);
    attr_done = 1;
  }

  // 1. fp32 -> fp16 converts
  cvt_f32_f16<<<8192, 256, 0, stream>>>(x, xh, NROWS * DM / 8);
  cvt_f32_f16<<<512, 256, 0, stream>>>(wq, wqh, DM * DM / 8);
  cvt_f32_f16<<<512, 256, 0, stream>>>(wk, wkh, DM * DM / 8);
  cvt_f32_f16<<<512, 256, 0, stream>>>(wv, wvh, DM * DM / 8);

  // 2. QKV projections (256x256 8-phase; grid = 256 blocks = 1/CU exactly)
  dim3 gp(DM / 256, NROWS / 256, 1);  // (4, 64)
  gemm256<0><<<gp, 512, 131072, stream>>>(xh, wqh, qh, DM, DM, DM, DM, 0, 0, 0);
  gemm256<0><<<gp, 512, 131072, stream>>>(xh, wkh, kh, DM, DM, DM, DM, 0, 0, 0);
  gemm256<3><<<gp, 512, 131072, stream>>>(xh, wvh, vth, DM, DM, DM, 0, 0, 0, 0);

  // 3. RoPE q,k in place
  rope_apply<<<NROWS * HALF_D / 256, 256, 0, stream>>>(qh);
  rope_apply<<<NROWS * HALF_D / 256, 256, 0, stream>>>(kh);

  // 4. scores (256-tile 8-phase GEMM; epilogue -> packed lower-tri 128-tiles)
  gemm256<1><<<dim3(SEQ / 256, SEQ / 256, BATCH), 512, 131072, stream>>>(
      qh, kh, Sp, DM, DM, DM, 128, (long long)SEQ * DM, (long long)SEQ * DM,
      (long long)NT128 * TILE_ELE);

  // 5. softmax rows -> fp16 P in place (unchanged)
  softmax_rows<<<NROWS, 256, 0, stream>>>(Sp);

  // 6. O = P @ V  (8-phase 128x256, heavy-first 1D grid, 512 blocks)
  gemm_pv<<<512, 512, 98304, stream>>>(Sp, vth, (float*)d_out);
}